// Round 13
// baseline (596.915 us; speedup 1.0000x reference)
//
#include <hip/hip_runtime.h>

#define B_ 4
#define S_ 2048
#define D_ 512
#define H_ 8

typedef __attribute__((ext_vector_type(8))) __bf16 bf16x8;
typedef __attribute__((ext_vector_type(4))) float f32x4;

#define NEGBIG  -1.442695040e9f          // -1e9 * log2(e): masks live in exp2 domain
#define QSCALE  0.18033688011112042f     // 0.125 * log2(e) folded into Q

// pack two floats -> two bf16 (RNE-ish, ties-up): 2 adds + 1 v_perm
__device__ __forceinline__ unsigned pack_rn(float a, float b) {
    union { float f; unsigned u; } ua, ub; ua.f = a; ub.f = b;
    return __builtin_amdgcn_perm(ub.u + 0x8000u, ua.u + 0x8000u, 0x07060302u);
}

// async global->LDS, 16B per lane. LDS dest = wave-uniform base + lane*16.
__device__ __forceinline__ void gl16(const void* g, void* l) {
    __builtin_amdgcn_global_load_lds(
        (const __attribute__((address_space(1))) unsigned int*)g,
        (__attribute__((address_space(3))) unsigned int*)l, 16, 0, 0);
}

struct MegaArgs {
    const float *q, *v; const int* am;
    const float *Wq, *Wk, *Wv, *Wo, *bq, *bk, *bv, *bo;
    unsigned short *Xbq, *Xbv, *Tq, *Tk, *Tv, *To;
    unsigned short *Qb, *Kb, *VtG, *ctx;
    int *idxc, *nv; float *Mf, *Mc; float* out;
    unsigned* bars;   // 3 counters (zeroed by hipMemsetAsync each launch)
};

#define NBLK 512u

// ---------------------------------------------------------------------------
// Hand-rolled grid barrier with explicit cross-XCD coherence (G16):
//  1. every thread drains its own stores (vmcnt), block-syncs;
//  2. tid0: system-scope release fence (L2 writeback), agent-scope arrive,
//     spin until all 512 blocks arrived, system-scope acquire fence (L2/L1
//     invalidate);
//  3. block-sync.
// All dirty lines are flushed before ANY block passes; all stale lines are
// dropped before any block reads. Counter zeroed by memsetAsync per launch
// (replay-safe). Deadlock-free: 512 blocks co-resident by construction
// (__launch_bounds__(256,2), LDS 48KB -> 2 blocks/CU).
// ---------------------------------------------------------------------------
__device__ __forceinline__ void grid_bar(unsigned* cnt) {
    asm volatile("s_waitcnt vmcnt(0) lgkmcnt(0)" ::: "memory");
    __syncthreads();
    if (threadIdx.x == 0) {
        __threadfence_system();
        __hip_atomic_fetch_add(cnt, 1u, __ATOMIC_RELEASE, __HIP_MEMORY_SCOPE_AGENT);
        while (__hip_atomic_load(cnt, __ATOMIC_ACQUIRE, __HIP_MEMORY_SCOPE_AGENT) < NBLK)
            __builtin_amdgcn_s_sleep(2);
        __threadfence_system();
    }
    __syncthreads();
}

// ---------------------------------------------------------------------------
// Phase PRE (item 0..4352): cast_x (4096) / cast_wt (256, uses smem) /
// compact+mask (1). Bodies verbatim from the verified r9 pre_all.
// ---------------------------------------------------------------------------
__device__ void phase_pre(char* smem, int it,
    const float* q, const float* v, const int* am,
    const float* Wq, const float* Wk, const float* Wv, const float* Wo,
    unsigned short* xq, unsigned short* xv,
    unsigned short* Tq, unsigned short* Tk, unsigned short* Tv, unsigned short* To,
    int* idxc, int* nvout, float* Mf, float* Mc)
{
    const int tid = threadIdx.x;
    if (it < 4096) {                        // ---- cast_x ----
        const int z = it >> 11, xb = it & 2047;
        const float* src = z ? v : q;
        unsigned short* dst = z ? xv : xq;
        int i = (xb * 256 + tid) * 8;
        float4 f0 = *(const float4*)&src[i];
        float4 f1 = *(const float4*)&src[i + 4];
        uint4 o;
        o.x = pack_rn(f0.x, f0.y); o.y = pack_rn(f0.z, f0.w);
        o.z = pack_rn(f1.x, f1.y); o.w = pack_rn(f1.z, f1.w);
        *(uint4*)&dst[i] = o;
    } else if (it < 4352) {                 // ---- cast_wt ----
        int r = it - 4096;
        int z = r >> 6, rem = r & 63;
        const float* W = (z == 0) ? Wq : (z == 1) ? Wk : (z == 2) ? Wv : Wo;
        unsigned short* T = (z == 0) ? Tq : (z == 1) ? Tk : (z == 2) ? Tv : To;
        int n0 = (rem & 7) * 64, k0 = (rem >> 3) * 64;
        float* Ts = (float*)smem;           // [64][69]
        #pragma unroll
        for (int itr = 0; itr < 4; itr++) {
            int lin = tid + itr * 256;
            int kr = lin >> 4, c4 = (lin & 15) * 4;
            float4 vv = *(const float4*)&W[(k0 + kr) * 512 + n0 + c4];
            Ts[kr * 69 + c4 + 0] = vv.x; Ts[kr * 69 + c4 + 1] = vv.y;
            Ts[kr * 69 + c4 + 2] = vv.z; Ts[kr * 69 + c4 + 3] = vv.w;
        }
        __syncthreads();
        int n = tid >> 2, kc = tid & 3;
        unsigned p[8];
        #pragma unroll
        for (int j = 0; j < 8; j++)
            p[j] = pack_rn(Ts[(kc * 16 + 2 * j) * 69 + n], Ts[(kc * 16 + 2 * j + 1) * 69 + n]);
        unsigned short* dst = &T[(n0 + n) * 512 + k0 + kc * 16];
        *(uint4*)dst       = *(uint4*)&p[0];
        *(uint4*)(dst + 8) = *(uint4*)&p[4];
    } else {                                // ---- compact + masks ----
        const int w = tid >> 6, lane = tid & 63;   // wave w = batch w
        const int* amb = am + w * 2048;
        int m[32];
        #pragma unroll
        for (int s = 0; s < 32; s++) m[s] = amb[s * 64 + lane];
        int* ib = idxc + w * 2048;
        const unsigned long long lt = (1ULL << lane) - 1ULL;
        int base = 0;
        #pragma unroll
        for (int s = 0; s < 32; s++) {
            unsigned long long bal = __ballot(m[s] != 0);
            if (m[s]) ib[base + __popcll(bal & lt)] = s * 64 + lane;
            base += __popcll(bal);
        }
        const int nv = base;
        for (int i = nv + lane; i < 2048; i += 64) ib[i] = 0;   // pad -> row 0
        float* mfb = Mf + w * 2048;
        float* mcb = Mc + w * 2048;
        #pragma unroll
        for (int s = 0; s < 32; s++) {
            int i = s * 64 + lane;
            mfb[i] = m[s] ? 0.f : NEGBIG;
            mcb[i] = (i < nv) ? 0.f : NEGBIG;
        }
        if (lane == 0) nvout[w] = nv;
    }
}

// ---------------------------------------------------------------------------
// Phase PROJ (z, r): r9/r6 proj_qkv body verbatim — 128x64 tiles, gl16
// double-buffer with counted vmcnt, source-side XOR swizzle, fused gather,
// early-exit. smem: AsP = 2x8192 shorts @0, BsP = 2x4096 shorts @32768.
// ---------------------------------------------------------------------------
__device__ void phase_proj(char* smem, int z, int r,
    const unsigned short* Xq, const unsigned short* Xv,
    const unsigned short* Wtq, const unsigned short* Wtk, const unsigned short* Wtv,
    const float* bq, const float* bk, const float* bv,
    const int* idxc, const int* nv1,
    unsigned short* Qb, unsigned short* Kb, unsigned short* VtG)
{
    const unsigned short* A  = (z == 0) ? Wtq : (z == 1) ? Wtk : Xv;
    const unsigned short* Bm = (z == 0) ? Xq  : (z == 1) ? Xv  : Wtv;
    const float* bias        = (z == 0) ? bq  : (z == 1) ? bk  : bv;
    const int m0 = (z < 2) ? (r >> 7) * 128 : (r >> 3) * 128;
    const int n0 = (z < 2) ? (r & 127) * 64 : (r & 7) * 64;

    if (z == 1) {
        int bb = n0 >> 11, cap = (nv1[bb] + 63) & ~63;
        if (cap < 64) cap = 64;
        if ((n0 & 2047) >= cap) return;
    }
    if (z == 2) {
        int bb = m0 >> 11, cap = (nv1[bb] + 63) & ~63;
        if (cap < 64) cap = 64;
        if ((m0 & 2047) >= cap) return;
    }

    unsigned short* AsP = (unsigned short*)smem;            // [2][8192]
    unsigned short* BsP = (unsigned short*)(smem + 32768);  // [2][4096]

    const int tid = threadIdx.x;
    const int w = tid >> 6, lane = tid & 63;
    const int l15 = lane & 15, quad = lane >> 4;
    const int wm = (w >> 1) * 64, wn = (w & 1) * 32;

    const int srw  = tid >> 3;                       // 0..31
    const int csrc = (tid & 7) ^ (srw & 7);
    const unsigned short* aS[4];
    const unsigned short* bS[2];
    #pragma unroll
    for (int is = 0; is < 4; is++) {
        int ra = m0 + is * 32 + srw;
        long sa = ra;
        if (z == 2) { int bb = ra >> 11; sa = (long)bb * 2048 + idxc[bb * 2048 + (ra & 2047)]; }
        aS[is] = A + sa * 512 + csrc * 8;
    }
    #pragma unroll
    for (int is = 0; is < 2; is++) {
        int rb = n0 + is * 32 + srw;
        long sb = rb;
        if (z == 1) { int bb = rb >> 11; sb = (long)bb * 2048 + idxc[bb * 2048 + (rb & 2047)]; }
        bS[is] = Bm + sb * 512 + csrc * 8;
    }

    const int koff0 = ((quad    ) ^ (l15 & 7)) * 8;  // undo swizzle on read
    const int koff1 = ((quad + 4) ^ (l15 & 7)) * 8;

    f32x4 acc[4][2];
    #pragma unroll
    for (int i = 0; i < 4; i++)
        #pragma unroll
        for (int j = 0; j < 2; j++) acc[i][j] = (f32x4){0.f, 0.f, 0.f, 0.f};

    #define STAGE_Q(buf, k0)                                                   \
        do {                                                                   \
            _Pragma("unroll")                                                  \
            for (int is = 0; is < 4; is++)                                     \
                gl16(aS[is] + (k0), AsP + (buf) * 8192 + is * 2048 + w * 512); \
            _Pragma("unroll")                                                  \
            for (int is = 0; is < 2; is++)                                     \
                gl16(bS[is] + (k0), BsP + (buf) * 4096 + is * 2048 + w * 512); \
        } while (0)

    STAGE_Q(0, 0);
    for (int k = 0; k < 8; k++) {
        const int cur = k & 1;
        if (k < 7) {
            STAGE_Q(cur ^ 1, (k + 1) * 64);
            asm volatile("s_waitcnt vmcnt(6)" ::: "memory");
        } else {
            asm volatile("s_waitcnt vmcnt(0)" ::: "memory");
        }
        asm volatile("s_barrier" ::: "memory");
        #pragma unroll
        for (int kc = 0; kc < 2; kc++) {
            const int ko = kc ? koff1 : koff0;
            bf16x8 a[4], bb[2];
            #pragma unroll
            for (int i = 0; i < 4; i++)
                a[i] = *(const bf16x8*)&AsP[cur * 8192 + (wm + 16 * i + l15) * 64 + ko];
            #pragma unroll
            for (int j = 0; j < 2; j++)
                bb[j] = *(const bf16x8*)&BsP[cur * 4096 + (wn + 16 * j + l15) * 64 + ko];
            #pragma unroll
            for (int i = 0; i < 4; i++)
                #pragma unroll
                for (int j = 0; j < 2; j++)
                    acc[i][j] = __builtin_amdgcn_mfma_f32_16x16x32_bf16(a[i], bb[j], acc[i][j], 0, 0, 0);
        }
        asm volatile("s_barrier" ::: "memory");
    }
    #undef STAGE_Q

    if (z == 2) {
        #pragma unroll
        for (int j = 0; j < 2; j++) {
            int N = n0 + wn + 16 * j + l15;
            float bv_ = bias[N];
            int h = N >> 6, d = N & 63;
            #pragma unroll
            for (int i = 0; i < 4; i++) {
                int Mb = m0 + wm + 16 * i + quad * 4;
                int b = Mb >> 11, s = Mb & 2047;
                uint2 o;
                o.x = pack_rn(acc[i][j][0] + bv_, acc[i][j][1] + bv_);
                o.y = pack_rn(acc[i][j][2] + bv_, acc[i][j][3] + bv_);
                *(uint2*)&VtG[((b * H_ + h) * 64 + d) * 2048 + s] = o;
            }
        }
    } else {
        unsigned short* dst = (z == 0) ? Qb : Kb;
        const float scale = (z == 0) ? QSCALE : 1.0f;
        #pragma unroll
        for (int j = 0; j < 2; j++) {
            int sg = n0 + wn + 16 * j + l15;
            int b = sg >> 11, s = sg & 2047;
            #pragma unroll
            for (int i = 0; i < 4; i++) {
                int F = m0 + wm + 16 * i + quad * 4;
                int h = F >> 6, d = F & 63;
                float4 b4 = *(const float4*)&bias[F];
                uint2 o;
                o.x = pack_rn((acc[i][j][0] + b4.x) * scale, (acc[i][j][1] + b4.y) * scale);
                o.y = pack_rn((acc[i][j][2] + b4.z) * scale, (acc[i][j][3] + b4.w) * scale);
                *(uint2*)&dst[((b * H_ + h) * 2048 + s) * 64 + d] = o;
            }
        }
    }
}

// ---------------------------------------------------------------------------
// Phase FLASH (bid 0..511): r9 pipelined flash body verbatim.
// smem: KsP = 2x4096 shorts @0, Ps @16384 (4 waves x 2048 shorts).
// ---------------------------------------------------------------------------
__device__ void phase_flash(char* smem, int bid,
    const unsigned short* Qg, const unsigned short* Kg,
    const unsigned short* VtG, const float* Mf,
    const float* Mc, const int* nvalid,
    unsigned short* ctxB)
{
    const int xcd = bid & 7, idx = bid >> 3;     // XCD x owns bh 4x..4x+3
    const int bh = xcd * 4 + (idx & 3);
    const int q0 = (idx >> 2) * 128;
    const int b = bh >> 3, h = bh & 7;

    const int tid = threadIdx.x;
    const int w = tid >> 6, lane = tid & 63;
    const int l15 = lane & 15, quad = lane >> 4;
    const int swz = l15 & 7;

    unsigned short* KsP = (unsigned short*)smem;            // [2][4096]
    unsigned short* pw  = (unsigned short*)(smem + 16384) + w * 2048;

    const int nv = nvalid[b];
    int ntiles = (nv + 63) >> 6;
    if (ntiles < 1) ntiles = 1;

    const float* mfb = Mf + b * 2048;
    const float* mcp = Mc + b * 2048 + quad * 4;

    bf16x8 qf[2][2];
    float mq[2];
    #pragma unroll
    for (int qb = 0; qb < 2; qb++) {
        int qrow = q0 + w * 32 + qb * 16 + l15;
        const unsigned short* p = &Qg[((long)bh * 2048 + qrow) * 64 + quad * 8];
        qf[qb][0] = *(const bf16x8*)p;
        qf[qb][1] = *(const bf16x8*)(p + 32);
        mq[qb] = mfb[qrow];
    }

    const unsigned short* vp[4];
    #pragma unroll
    for (int i = 0; i < 4; i++)
        vp[i] = VtG + ((long)bh * 64 + i * 16 + l15) * 2048 + quad * 8;

    const int srow = tid >> 2;
    const int sch  = (tid & 3) * 2;
    const unsigned short* kgb = Kg + (long)bh * 2048 * 64;
    const int sw0 = srow * 64 + ((sch    ) ^ (srow & 7)) * 8;
    const int sw1 = srow * 64 + ((sch + 1) ^ (srow & 7)) * 8;

    {
        uint4 a = *(const uint4*)&kgb[srow * 64 + sch * 8];
        uint4 c = *(const uint4*)&kgb[srow * 64 + sch * 8 + 8];
        *(uint4*)&KsP[sw0] = a;
        *(uint4*)&KsP[sw1] = c;
    }
    const int kt1 = (ntiles > 1) ? 64 : 0;
    uint4 kstA = *(const uint4*)&kgb[(kt1 + srow) * 64 + sch * 8];
    uint4 kstB = *(const uint4*)&kgb[(kt1 + srow) * 64 + sch * 8 + 8];

    const int koff0 = ((quad    ) ^ swz) * 8;
    const int koff1 = ((quad + 4) ^ swz) * 8;

    f32x4 accO[2][4];
    #pragma unroll
    for (int qb = 0; qb < 2; qb++)
        #pragma unroll
        for (int dt = 0; dt < 4; dt++) accO[qb][dt] = (f32x4){0.f, 0.f, 0.f, 0.f};
    float mi[2] = {-3.0e38f, -3.0e38f};
    float li[2] = {0.f, 0.f};

    __syncthreads();

    // QK(0) into scA (prologue)
    f32x4 scA[2][4], scB[2][4];
    {
        f32x4 kmf[4];
        #pragma unroll
        for (int nt = 0; nt < 4; nt++)
            kmf[nt] = *(const f32x4*)(mcp + nt * 16);
        bf16x8 kf[4][2];
        #pragma unroll
        for (int nt = 0; nt < 4; nt++) {
            kf[nt][0] = *(const bf16x8*)&KsP[(nt * 16 + l15) * 64 + koff0];
            kf[nt][1] = *(const bf16x8*)&KsP[(nt * 16 + l15) * 64 + koff1];
        }
        #pragma unroll
        for (int qb = 0; qb < 2; qb++)
            #pragma unroll
            for (int nt = 0; nt < 4; nt++) {
                f32x4 c = kmf[nt];
                c[0] += mq[qb]; c[1] += mq[qb]; c[2] += mq[qb]; c[3] += mq[qb];
                c = __builtin_amdgcn_mfma_f32_16x16x32_bf16(kf[nt][0], qf[qb][0], c, 0, 0, 0);
                c = __builtin_amdgcn_mfma_f32_16x16x32_bf16(kf[nt][1], qf[qb][1], c, 0, 0, 0);
                scA[qb][nt] = c;
            }
    }

    auto STEP = [&](f32x4 (&scCur)[2][4], f32x4 (&scNxt)[2][4], int t) {
        const int kt = t * 64;
        const int n = (t & 1) ^ 1;
        const bool hasNext = (t + 1 < ntiles);
        const int kt2 = (t + 2 < ntiles) ? (t + 2) * 64 : (ntiles - 1) * 64;

        bf16x8 vf[4][2];
        #pragma unroll
        for (int dt = 0; dt < 4; dt++) {
            vf[dt][0] = *(const bf16x8*)(vp[dt] + kt);
            vf[dt][1] = *(const bf16x8*)(vp[dt] + kt + 32);
        }
        uint4 k2A = *(const uint4*)&kgb[(kt2 + srow) * 64 + sch * 8];
        uint4 k2B = *(const uint4*)&kgb[(kt2 + srow) * 64 + sch * 8 + 8];
        f32x4 kmf[4];
        #pragma unroll
        for (int nt = 0; nt < 4; nt++)
            kmf[nt] = *(const f32x4*)(mcp + kt + 64 + nt * 16);

        *(uint4*)&KsP[n * 4096 + sw0] = kstA;
        *(uint4*)&KsP[n * 4096 + sw1] = kstB;
        __syncthreads();
        kstA = k2A; kstB = k2B;

        if (hasNext) {
            bf16x8 kf[4][2];
            #pragma unroll
            for (int nt = 0; nt < 4; nt++) {
                kf[nt][0] = *(const bf16x8*)&KsP[n * 4096 + (nt * 16 + l15) * 64 + koff0];
                kf[nt][1] = *(const bf16x8*)&KsP[n * 4096 + (nt * 16 + l15) * 64 + koff1];
            }
            #pragma unroll
            for (int qb = 0; qb < 2; qb++)
                #pragma unroll
                for (int nt = 0; nt < 4; nt++) {
                    f32x4 c = kmf[nt];
                    c[0] += mq[qb]; c[1] += mq[qb]; c[2] += mq[qb]; c[3] += mq[qb];
                    c = __builtin_amdgcn_mfma_f32_16x16x32_bf16(kf[nt][0], qf[qb][0], c, 0, 0, 0);
                    c = __builtin_amdgcn_mfma_f32_16x16x32_bf16(kf[nt][1], qf[qb][1], c, 0, 0, 0);
                    scNxt[qb][nt] = c;
                }
        }

        #pragma unroll
        for (int qb = 0; qb < 2; qb++) {
            float mloc = fmaxf(fmaxf(scCur[qb][0][0], scCur[qb][0][1]),
                               fmaxf(scCur[qb][0][2], scCur[qb][0][3]));
            #pragma unroll
            for (int nt = 1; nt < 4; nt++)
                mloc = fmaxf(mloc, fmaxf(fmaxf(scCur[qb][nt][0], scCur[qb][nt][1]),
                                         fmaxf(scCur[qb][nt][2], scCur[qb][nt][3])));
            mloc = fmaxf(mloc, __shfl_xor(mloc, 16));
            mloc = fmaxf(mloc, __shfl_xor(mloc, 32));

            float mn = mi[qb];
            if (!__all(mloc <= mn + 4.f)) {      // defer-max: P bounded by 2^4
                float mo = mn;
                mn = fmaxf(mo, mloc);
                float alpha = __builtin_amdgcn_exp2f(mo - mn);
                li[qb] *= alpha;
                #pragma unroll
                for (int dt = 0; dt < 4; dt++) {
                    accO[qb][dt][0] *= alpha; accO[qb][dt][1] *= alpha;
                    accO[qb][dt][2] *= alpha; accO[qb][dt][3] *= alpha;
                }
                mi[qb] = mn;
            }

            float ps = 0.f;
            const int prbase = (qb * 16 + l15) * 64;
            #pragma unroll
            for (int nt = 0; nt < 4; nt++) {
                float p0 = __builtin_amdgcn_exp2f(scCur[qb][nt][0] - mn);
                float p1 = __builtin_amdgcn_exp2f(scCur[qb][nt][1] - mn);
                float p2 = __builtin_amdgcn_exp2f(scCur[qb][nt][2] - mn);
                float p3 = __builtin_amdgcn_exp2f(scCur[qb][nt][3] - mn);
                ps += (p0 + p1) + (p2 + p3);
                uint2 pp;
                pp.x = pack_rn(p0, p1);
                pp.y = pack_rn(p2, p3);
                *(uint2*)&pw[prbase + ((2 * nt + (quad >> 1)) ^ swz) * 8 + (quad & 1) * 4] = pp;
            }
            ps += __shfl_xor(ps, 16);
            ps += __shfl_xor(ps, 32);
            li[qb] += ps;
        }

        #pragma unroll
        for (int qb = 0; qb < 2; qb++) {
            bf16x8 pf0 = *(const bf16x8*)&pw[(qb * 16 + l15) * 64 + koff0];
            bf16x8 pf1 = *(const bf16x8*)&pw[(qb * 16 + l15) * 64 + koff1];
            __builtin_amdgcn_s_setprio(1);
            #pragma unroll
            for (int dt = 0; dt < 4; dt++) {
                accO[qb][dt] = __builtin_amdgcn_mfma_f32_16x16x32_bf16(
                    vf[dt][0], pf0, accO[qb][dt], 0, 0, 0);
                accO[qb][dt] = __builtin_amdgcn_mfma_f32_16x16x32_bf16(
                    vf[dt][1], pf1, accO[qb][dt], 0, 0, 0);
            }
            __builtin_amdgcn_s_setprio(0);
        }
    };

    for (int t = 0; t < ntiles; t += 2) {
        STEP(scA, scB, t);
        if (t + 1 < ntiles) STEP(scB, scA, t + 1);
    }

    #pragma unroll
    for (int qb = 0; qb < 2; qb++) {
        float inv = 1.f / li[qb];
        int qq = q0 + w * 32 + qb * 16 + l15;
        int obase = (b * 2048 + qq) * 512 + h * 64 + quad * 4;
        #pragma unroll
        for (int dt = 0; dt < 4; dt++) {
            uint2 o;
            o.x = pack_rn(accO[qb][dt][0] * inv, accO[qb][dt][1] * inv);
            o.y = pack_rn(accO[qb][dt][2] * inv, accO[qb][dt][3] * inv);
            *(uint2*)&ctxB[obase + dt * 16] = o;
        }
    }
}

// ---------------------------------------------------------------------------
// Phase OUT (r 0..511): r9/r6 proj_out body verbatim (128x64 tiles, gl16 DB,
// counted vmcnt). smem layout same as phase_proj.
// ---------------------------------------------------------------------------
__device__ void phase_out(char* smem, int r,
    const unsigned short* ctxB, const unsigned short* Wto,
    const float* bo, float* out)
{
    const int m0 = (r >> 7) * 128, n0 = (r & 127) * 64;
    unsigned short* AsP = (unsigned short*)smem;            // [2][8192]
    unsigned short* BsP = (unsigned short*)(smem + 32768);  // [2][4096]

    const int tid = threadIdx.x;
    const int w = tid >> 6, lane = tid & 63;
    const int l15 = lane & 15, quad = lane >> 4;
    const int wm = (w >> 1) * 64, wn = (w & 1) * 32;

    const int srw  = tid >> 3;
    const int csrc = (tid & 7) ^ (srw & 7);
    const unsigned short* aS[4];
    const unsigned short* bS[2];
    #pragma unroll
    for (int is = 0; is < 4; is++)
        aS[is] = Wto  + (long)(m0 + is * 32 + srw) * 512 + csrc * 8;
    #pragma unroll
    for (int is = 0; is < 2; is++)
        bS[is] = ctxB + (long)(n0 + is * 32 + srw) * 512 + csrc * 8;

    const int koff0 = ((quad    ) ^ (l15 & 7)) * 8;
    const int koff1 = ((quad + 4) ^ (l15 & 7)) * 8;

    f32x4 acc[4][2];
    #pragma unroll
    for (int i = 0; i < 4; i++)
        #pragma unroll
        for (int j = 0; j < 2; j++) acc[i][j] = (f32x4){0.f, 0.f, 0.f, 0.f};

    #define STAGE_O(buf, k0)                                                   \
        do {                                                                   \
            _Pragma("unroll")                                                  \
            for (int is = 0; is < 4; is++)                                     \
                gl16(aS[is] + (k0), AsP + (buf) * 8192 + is * 2048 + w * 512); \
            _Pragma("unroll")                                                  \
            for (int is = 0; is < 2; is++)                                     \
                gl16(bS[is] + (k0), BsP + (buf) * 4096 + is * 2048 + w * 512); \
        } while (0)

    STAGE_O(0, 0);
    for (int k = 0; k < 8; k++) {
        const int cur = k & 1;
        if (k < 7) {
            STAGE_O(cur ^ 1, (k + 1) * 64);
            asm volatile("s_waitcnt vmcnt(6)" ::: "memory");
        } else {
            asm volatile("s_waitcnt vmcnt(0)" ::: "memory");
        }
        asm volatile("s_barrier" ::: "memory");
        #pragma unroll
        for (int kc = 0; kc < 2; kc++) {
            const int ko = kc ? koff1 : koff0;
            bf16x8 a[4], bb[2];
            #pragma unroll
            for (int i = 0; i < 4; i++)
                a[i] = *(const bf16x8*)&AsP[cur * 8192 + (wm + 16 * i + l15) * 64 + ko];
            #pragma unroll
            for (int j = 0; j < 2; j++)
                bb[j] = *(const bf16x8*)&BsP[cur * 4096 + (wn + 16 * j + l15) * 64 + ko];
            #pragma unroll
            for (int i = 0; i < 4; i++)
                #pragma unroll
                for (int j = 0; j < 2; j++)
                    acc[i][j] = __builtin_amdgcn_mfma_f32_16x16x32_bf16(a[i], bb[j], acc[i][j], 0, 0, 0);
        }
        asm volatile("s_barrier" ::: "memory");
    }
    #undef STAGE_O

    #pragma unroll
    for (int j = 0; j < 2; j++) {
        int sg = n0 + wn + 16 * j + l15;
        #pragma unroll
        for (int i = 0; i < 4; i++) {
            int F = m0 + wm + 16 * i + quad * 4;
            float4 b4 = *(const float4*)&bo[F];
            float4 vv;
            vv.x = acc[i][j][0] + b4.x;
            vv.y = acc[i][j][1] + b4.y;
            vv.z = acc[i][j][2] + b4.z;
            vv.w = acc[i][j][3] + b4.w;
            *(float4*)&out[sg * 512 + F] = vv;
        }
    }
}

// ---------------------------------------------------------------------------
// Megakernel, PLAIN launch (no cooperative API): 512 blocks x 256 threads,
// co-resident by construction (launch_bounds(256,2): VGPR<=256, LDS 48KB ->
// 2 blocks/CU; 512 <= 2x256). Own grid barrier (workspace counters zeroed by
// memsetAsync each launch) with system-scope fences for cross-XCD coherence.
// ---------------------------------------------------------------------------
__global__ void __launch_bounds__(256, 2) mha_mega(MegaArgs a)
{
    __shared__ __align__(16) char smem[49152];
    const int bid = blockIdx.x;

    for (int it = bid; it < 4353; it += 512) {
        phase_pre(smem, it, a.q, a.v, a.am, a.Wq, a.Wk, a.Wv, a.Wo,
                  a.Xbq, a.Xbv, a.Tq, a.Tk, a.Tv, a.To, a.idxc, a.nv, a.Mf, a.Mc);
        __syncthreads();          // LDS (Ts) reuse between pre items
    }
    grid_bar(a.bars + 0);

    for (int z = 0; z < 3; ++z) { // each block: one z=0, one z=1, one z=2 tile
        phase_proj(smem, z, bid, a.Xbq, a.Xbv, a.Tq, a.Tk, a.Tv,
                   a.bq, a.bk, a.bv, a.idxc, a.nv, a.Qb, a.Kb, a.VtG);
        __syncthreads();
    }
    grid_bar(a.bars + 16);

    phase_flash(smem, bid, a.Qb, a.Kb, a.VtG, a.Mf, a.Mc, a.nv, a.ctx);
    grid_bar(a.bars + 32);

    phase_out(smem, bid, a.ctx, a.To, a.bo, a.out);
}

extern "C" void kernel_launch(void* const* d_in, const int* in_sizes, int n_in,
                              void* d_out, int out_size, void* d_ws, size_t ws_size,
                              hipStream_t stream)
{
    char* ws = (char*)d_ws;
    const size_t MB = 1 << 20;
    const size_t KB = 1 << 10;

    MegaArgs a;
    a.q  = (const float*)d_in[0];
    a.v  = (const float*)d_in[1];
    a.am = (const int*)d_in[2];
    a.Wq = (const float*)d_in[3];  a.bq = (const float*)d_in[4];
    a.Wk = (const float*)d_in[5];  a.bk = (const float*)d_in[6];
    a.Wv = (const float*)d_in[7];  a.bv = (const float*)d_in[8];
    a.Wo = (const float*)d_in[9];  a.bo = (const float*)d_in[10];
    a.out = (float*)d_out;

    a.Xbq = (unsigned short*)(ws);                   // 8 MB bf16
    a.Xbv = (unsigned short*)(ws + 8 * MB);          // 8 MB
    a.Tq  = (unsigned short*)(ws + 16 * MB);         // 0.5 MB each
    a.Tk  = (unsigned short*)(ws + 16 * MB + MB / 2);
    a.Tv  = (unsigned short*)(ws + 17 * MB);
    a.To  = (unsigned short*)(ws + 17 * MB + MB / 2);
    a.Qb  = (unsigned short*)(ws + 18 * MB);         // 8 MB (bh,s,d)
    a.Kb  = (unsigned short*)(ws + 26 * MB);         // 8 MB (bh,i,d) compacted
    a.VtG = (unsigned short*)(ws + 34 * MB);         // 8 MB (bh,d,i) compacted
    a.idxc = (int*)(ws + 42 * MB);                   // 32 KB
    a.Mf   = (float*)(ws + 42 * MB + 32 * KB);       // 32 KB
    a.Mc   = (float*)(ws + 42 * MB + 64 * KB);       // 32 KB
    a.nv   = (int*)(ws + 42 * MB + 96 * KB);         // 16 B
    a.bars = (unsigned*)(ws + 42 * MB + 100 * KB);   // 3 counters, 64B apart
    a.ctx  = a.Xbq;  // Xbq dead after proj phase; flash writes, out reads

    hipMemsetAsync(a.bars, 0, 256, stream);          // zero barrier counters
    mha_mega<<<dim3(512), dim3(256), 0, stream>>>(a);
}